// Round 2
// 389.056 us; speedup vs baseline: 1.0015x; 1.0015x over previous
//
#include <hip/hip_runtime.h>

typedef unsigned short u16;
typedef short bf16x8 __attribute__((ext_vector_type(8)));
typedef float f32x4 __attribute__((ext_vector_type(4)));

#define MFMA16(a,b,c) __builtin_amdgcn_mfma_f32_16x16x32_bf16((a),(b),(c),0,0,0)
#define NEGHUGE (-1.0e30f)

__device__ __forceinline__ u16 f2b(float f){
  union { float f; unsigned int i; } v; v.f = f;
  unsigned int r = v.i + 0x7FFFu + ((v.i>>16)&1u);
  return (u16)(r>>16);
}

union BfPack { u16 h[8]; bf16x8 v; uint4 u; };

__device__ __forceinline__ uint4 pack8u(const float* __restrict__ p){
  float4 a = *(const float4*)p;
  float4 b = *(const float4*)(p + 4);
  BfPack r;
  r.h[0]=f2b(a.x); r.h[1]=f2b(a.y); r.h[2]=f2b(a.z); r.h[3]=f2b(a.w);
  r.h[4]=f2b(b.x); r.h[5]=f2b(b.y); r.h[6]=f2b(b.z); r.h[7]=f2b(b.w);
  return r.u;
}

// async 16B global -> LDS; LDS dest is wave-uniform base + lane*16
__device__ __forceinline__ void gld_lds16(const u16* g, u16* l){
  __builtin_amdgcn_global_load_lds(
      (const __attribute__((address_space(1))) unsigned int*)g,
      (__attribute__((address_space(3))) unsigned int*)l, 16, 0, 0);
}

// ---------------- kernel 1: f32 -> bf16 for x, w_qkv, w_out ------------------
// 8 floats per thread; exact: x 2,408,448 | wqkv 55,296 | wout 18,432 groups
__global__ __launch_bounds__(256) void k_convert(
    const float* __restrict__ x, const float* __restrict__ wqkv,
    const float* __restrict__ wout,
    u16* __restrict__ xb, u16* __restrict__ wqkvb, u16* __restrict__ woutb)
{
  int idx = (int)blockIdx.x * 256 + threadIdx.x;      // 8-float groups
  const float* src; u16* dst; int off;
  if (idx < 2408448)      { src = x;    dst = xb;    off = idx; }
  else if (idx < 2463744) { src = wqkv; dst = wqkvb; off = idx - 2408448; }
  else                    { src = wout; dst = woutb; off = idx - 2463744; }
  *(uint4*)(dst + (size_t)off*8) = pack8u(src + (size_t)off*8);
}

// ---------------- kernel 2: QKV GEMM ------------------------------------------
// A-tile staged via async global_load_lds (bf16 x, shift folded into source
// addr). LDS is linear [64][384]; bank conflicts avoided by XOR-swizzling the
// 16B chunk index with (row&7) on the global SOURCE address and on every LDS
// read (both-sides swizzle, m173/m201 pattern). XCD-bijective block swizzle
// keeps the 3 n-group blocks of each m-tile on one XCD L2 (2352 = 8*294).
__global__ __launch_bounds__(384, 4) void k_qkv(
    const u16* __restrict__ xb, const u16* __restrict__ wqkvb,
    u16* __restrict__ qkvs)
{
  __shared__ u16 At[64][384];   // linear, 49152 B; reused as output staging
  u16* Al = &At[0][0];
  const int tid = threadIdx.x;
  const int wv = tid >> 6, lane = tid & 63, quad = lane >> 4, l16 = lane & 15;

  const int bid = (int)blockIdx.x;                    // 2352 blocks
  const int logical = (bid & 7) * 294 + (bid >> 3);   // bijective XCD swizzle
  const int m0 = (logical / 3) * 64;
  const int ng = logical % 3;
  const int n0 = (ng * 6 + wv) * 64;

  // async stage: wave wv fills LDS bytes [wv*8192, wv*8192+8192), 8 issues
  {
    const int lane16 = lane << 4;
    #pragma unroll
    for (int i = 0; i < 8; ++i) {
      const int Lbase = wv*8192 + i*1024;             // wave-uniform
      const int L  = Lbase + lane16;                  // this lane's LDS byte
      const int r  = L / 768;                         // logical row 0..63
      const int cp = (L % 768) >> 4;                  // physical 16B chunk
      const int cl = cp ^ (r & 7);                    // logical chunk (XOR inv)
      const int m  = m0 + r;
      const int b  = m / 3136, rm = m - b*3136;
      const int hs = rm / 56, ws_ = rm - hs*56;
      int h = hs + 3; if (h >= 56) h -= 56;           // shifted source coord
      int w = ws_ + 3; if (w >= 56) w -= 56;
      gld_lds16(xb + (size_t)((b*56 + h)*56 + w)*384 + cl*8,
                Al + Lbase/2);
    }
  }
  __syncthreads();

  f32x4 acc[4][4];
  #pragma unroll
  for (int mi = 0; mi < 4; ++mi)
    #pragma unroll
    for (int j = 0; j < 4; ++j) acc[mi][j] = f32x4{0.f,0.f,0.f,0.f};

  const int swz = l16 & 7;     // (row&7) for row = mi*16+l16
  for (int k = 0; k < 12; ++k) {
    bf16x8 a[4], bb[4];
    const int ck = ((k*4 + quad) ^ swz) << 3;         // swizzled col (u16)
    #pragma unroll
    for (int mi = 0; mi < 4; ++mi)
      a[mi] = *(const bf16x8*)(Al + (mi*16 + l16)*384 + ck);
    #pragma unroll
    for (int j = 0; j < 4; ++j)
      bb[j] = *(const bf16x8*)(&wqkvb[(size_t)(n0 + j*16 + l16)*384 + k*32 + quad*8]);
    #pragma unroll
    for (int mi = 0; mi < 4; ++mi)
      #pragma unroll
      for (int j = 0; j < 4; ++j)
        acc[mi][j] = MFMA16(a[mi], bb[j], acc[mi][j]);
  }
  __syncthreads();   // A-tile reads done; reuse At as output staging

  #pragma unroll
  for (int mi = 0; mi < 4; ++mi)
    #pragma unroll
    for (int j = 0; j < 4; ++j)
      #pragma unroll
      for (int r = 0; r < 4; ++r) {
        const int row = mi*16 + quad*4 + r;
        const int c = wv*8 + j*2 + (l16 >> 3);        // logical 16B chunk
        Al[row*384 + (((c ^ (row & 7)) << 3) | (l16 & 7))] = f2b(acc[mi][j][r]);
      }
  __syncthreads();

  // cooperative coalesced store: 64 rows x 768 B contiguous spans
  for (int i = tid; i < 64*48; i += 384) {
    int row = i / 48, g = i % 48;
    *(uint4*)(qkvs + (size_t)(m0 + row)*1152 + ng*384 + g*8) =
        *(const uint4*)(Al + row*384 + ((g ^ (row & 7)) << 3));
  }
}

// ---------------- kernel 3: windowed attention, 1 wave per (window, head) -----
// Output written at ORIGINAL (rolled +3) coordinates so k_proj is fully linear.
struct __align__(16) SmemT {
  u16 Vt[4][32][72];    // per-wave V^T [d][pos]; pos 49..63 zeroed
  u16 P[4][64][72];     // per-wave softmax probs
  float relb[4][169];   // per-wave rel-pos table column
};

__global__ __launch_bounds__(256) void k_attn(
    const u16* __restrict__ qkvs, const float* __restrict__ relt,
    u16* __restrict__ attnb)
{
  __shared__ SmemT S;
  const int tid = threadIdx.x;
  const int wv = tid >> 6, lane = tid & 63, quad = lane >> 4, l16 = lane & 15;
  const int blk = (int)blockIdx.x;                 // 3072 blocks
  const int b = blk / 192, r0 = blk % 192, win = r0 / 3, hg = r0 % 3;
  const int hb = win >> 3, wb = win & 7, head = hg*4 + wv;

  for (int i = lane; i < 169; i += 64) S.relb[wv][i] = relt[i*12 + head];

  // stage V^T: lane = pos
  {
    const int pos = lane;
    u16 vh[32];
    if (pos < 49) {
      int py = pos / 7, px = pos - py*7;
      const uint4* src = (const uint4*)(qkvs +
          (size_t)((b*56 + hb*7+py)*56 + wb*7+px)*1152 + 768 + head*32);
      #pragma unroll
      for (int t = 0; t < 4; ++t) *(uint4*)(&vh[t*8]) = src[t];
    } else {
      #pragma unroll
      for (int t = 0; t < 4; ++t) *(uint4*)(&vh[t*8]) = uint4{0,0,0,0};
    }
    #pragma unroll
    for (int d = 0; d < 32; ++d) S.Vt[wv][d][pos] = vh[d];
  }

  // Q / K fragments straight from global (A: m=pos, B: n=pos; k = quad*8..)
  bf16x8 aq[4], bk[4];
  #pragma unroll
  for (int mt = 0; mt < 4; ++mt) {
    int pos = mt*16 + l16; if (pos > 48) pos = 48;   // clamp; masked later
    int py = pos / 7, px = pos - py*7;
    const u16* src = qkvs + (size_t)((b*56 + hb*7+py)*56 + wb*7+px)*1152
                   + head*32 + quad*8;
    aq[mt] = *(const bf16x8*)src;          // Q part
    bk[mt] = *(const bf16x8*)(src + 384);  // K part
  }
  __syncthreads();

  // QK^T
  f32x4 sc[4][4];
  #pragma unroll
  for (int mt = 0; mt < 4; ++mt)
    #pragma unroll
    for (int n = 0; n < 4; ++n) {
      f32x4 z = {0.f,0.f,0.f,0.f};
      sc[mt][n] = MFMA16(aq[mt], bk[n], z);
    }

  // bias + mask + softmax
  #pragma unroll
  for (int mt = 0; mt < 4; ++mt)
    #pragma unroll
    for (int r = 0; r < 4; ++r) {
      const int q = mt*16 + quad*4 + r;
      const int qy = q / 7, qx = q - qy*7;
      #pragma unroll
      for (int n = 0; n < 4; ++n) {
        const int key = n*16 + l16;
        float s = sc[mt][n][r] * 0.17677669529663687f;   // 1/sqrt(32)
        if (key < 49 && q < 49) {
          const int ky = key / 7, kx = key - ky*7;
          s += S.relb[wv][(ky - qy + 6)*13 + (kx - qx + 6)];
          if (hb == 7 && ((qy >= 4) != (ky >= 4))) s = NEGHUGE;  // UL mask
        } else {
          s = NEGHUGE;
        }
        sc[mt][n][r] = s;
      }
      float mx = fmaxf(fmaxf(sc[mt][0][r], sc[mt][1][r]),
                       fmaxf(sc[mt][2][r], sc[mt][3][r]));
      mx = fmaxf(mx, __shfl_xor(mx, 1));
      mx = fmaxf(mx, __shfl_xor(mx, 2));
      mx = fmaxf(mx, __shfl_xor(mx, 4));
      mx = fmaxf(mx, __shfl_xor(mx, 8));
      float sum = 0.f;
      #pragma unroll
      for (int n = 0; n < 4; ++n) {
        float p = exp2f((sc[mt][n][r] - mx) * 1.4426950408889634f);
        sc[mt][n][r] = p; sum += p;
      }
      sum += __shfl_xor(sum, 1);
      sum += __shfl_xor(sum, 2);
      sum += __shfl_xor(sum, 4);
      sum += __shfl_xor(sum, 8);
      const float rinv = 1.0f / sum;
      #pragma unroll
      for (int n = 0; n < 4; ++n)
        S.P[wv][q][n*16 + l16] = f2b(sc[mt][n][r] * rinv);
    }
  __syncthreads();

  // PV; store at rolled (+3) coordinates
  #pragma unroll
  for (int mt = 0; mt < 4; ++mt) {
    bf16x8 ap0 = *(const bf16x8*)(&S.P[wv][mt*16 + l16][quad*8]);
    bf16x8 ap1 = *(const bf16x8*)(&S.P[wv][mt*16 + l16][32 + quad*8]);
    #pragma unroll
    for (int n2 = 0; n2 < 2; ++n2) {
      bf16x8 bv0 = *(const bf16x8*)(&S.Vt[wv][n2*16 + l16][quad*8]);
      bf16x8 bv1 = *(const bf16x8*)(&S.Vt[wv][n2*16 + l16][32 + quad*8]);
      f32x4 o = {0.f,0.f,0.f,0.f};
      o = MFMA16(ap0, bv0, o);
      o = MFMA16(ap1, bv1, o);
      #pragma unroll
      for (int r = 0; r < 4; ++r) {
        int q = mt*16 + quad*4 + r;
        if (q < 49) {
          int py = q / 7, px = q - py*7;
          int hh = hb*7 + py + 3; if (hh >= 56) hh -= 56;  // inverse roll here
          int ww = wb*7 + px + 3; if (ww >= 56) ww -= 56;
          attnb[(size_t)((b*56 + hh)*56 + ww)*384
                + head*32 + n2*16 + l16] = f2b(o[r]);
        }
      }
    }
  }
}

// ---------------- kernel 4: out = attn @ w_out^T + b_out, fully linear -------
// A-tile staged via async global_load_lds with the same both-sides XOR swizzle.
__global__ __launch_bounds__(384, 4) void k_proj(
    const u16* __restrict__ attnb, const u16* __restrict__ woutb,
    const float* __restrict__ bout, float* __restrict__ out)
{
  __shared__ u16 At[32][384];   // linear, 24576 B
  u16* Al = &At[0][0];
  const int tid = threadIdx.x;
  const int wv = tid >> 6, lane = tid & 63, quad = lane >> 4, l16 = lane & 15;
  const int m0 = (int)blockIdx.x * 32;               // 1568 blocks
  const int n0 = wv * 64;                            // 6 waves cover N=384

  {
    const int lane16 = lane << 4;
    #pragma unroll
    for (int i = 0; i < 4; ++i) {
      const int Lbase = wv*4096 + i*1024;            // wave-uniform
      const int L  = Lbase + lane16;
      const int r  = L / 768;
      const int cp = (L % 768) >> 4;
      const int cl = cp ^ (r & 7);
      gld_lds16(attnb + (size_t)(m0 + r)*384 + cl*8, Al + Lbase/2);
    }
  }
  __syncthreads();

  f32x4 acc[2][4];
  #pragma unroll
  for (int mi = 0; mi < 2; ++mi)
    #pragma unroll
    for (int j = 0; j < 4; ++j) acc[mi][j] = f32x4{0.f,0.f,0.f,0.f};

  const int swz = l16 & 7;
  for (int k = 0; k < 12; ++k) {
    bf16x8 a[2], bb[4];
    const int ck = ((k*4 + quad) ^ swz) << 3;
    #pragma unroll
    for (int mi = 0; mi < 2; ++mi)
      a[mi] = *(const bf16x8*)(Al + (mi*16 + l16)*384 + ck);
    #pragma unroll
    for (int j = 0; j < 4; ++j)
      bb[j] = *(const bf16x8*)(&woutb[(size_t)(n0 + j*16 + l16)*384 + k*32 + quad*8]);
    #pragma unroll
    for (int mi = 0; mi < 2; ++mi)
      #pragma unroll
      for (int j = 0; j < 4; ++j)
        acc[mi][j] = MFMA16(a[mi], bb[j], acc[mi][j]);
  }

  float bias[4];
  #pragma unroll
  for (int j = 0; j < 4; ++j) bias[j] = bout[n0 + j*16 + l16];

  // linear stores; j-inner so the 4x64B segments of each 256B span merge
  #pragma unroll
  for (int mi = 0; mi < 2; ++mi)
    #pragma unroll
    for (int r = 0; r < 4; ++r) {
      const int m = m0 + mi*16 + quad*4 + r;
      float* dst = out + (size_t)m*384 + n0;
      #pragma unroll
      for (int j = 0; j < 4; ++j)
        dst[j*16 + l16] = acc[mi][j][r] + bias[j];
    }
}

extern "C" void kernel_launch(void* const* d_in, const int* in_sizes, int n_in,
                              void* d_out, int out_size, void* d_ws, size_t ws_size,
                              hipStream_t stream) {
  const float* x    = (const float*)d_in[0];
  const float* wqkv = (const float*)d_in[1];
  const float* wout = (const float*)d_in[2];
  const float* bout = (const float*)d_in[3];
  const float* relt = (const float*)d_in[4];

  char* ws = (char*)d_ws;
  u16* qkvs  = (u16*)(ws);                        // 115,605,504 B
  u16* wqkvb = (u16*)(ws + 115605504);            //     884,736 B
  u16* woutb = (u16*)(ws + 116490240);            //     294,912 B
  // xb (bf16 x) and attnb alias the same slot: xb is dead before k_attn runs
  u16* xb    = (u16*)(ws + 116785152);            //  38,535,168 B
  u16* attnb = (u16*)(ws + 116785152);            //  38,535,168 B
  float* outp = (float*)d_out;

  k_convert<<<9696, 256, 0, stream>>>(x, wqkv, wout, xb, wqkvb, woutb);
  k_qkv<<<2352, 384, 0, stream>>>(xb, wqkvb, qkvs);
  k_attn<<<3072, 256, 0, stream>>>(qkvs, relt, attnb);
  k_proj<<<1568, 384, 0, stream>>>(attnb, woutb, bout, outp);
}

// Round 3
// 358.616 us; speedup vs baseline: 1.0865x; 1.0849x over previous
//
#include <hip/hip_runtime.h>

typedef unsigned short u16;
typedef short bf16x8 __attribute__((ext_vector_type(8)));
typedef float f32x4 __attribute__((ext_vector_type(4)));

#define MFMA16(a,b,c) __builtin_amdgcn_mfma_f32_16x16x32_bf16((a),(b),(c),0,0,0)
#define NEGHUGE (-1.0e30f)

__device__ __forceinline__ u16 f2b(float f){
  union { float f; unsigned int i; } v; v.f = f;
  unsigned int r = v.i + 0x7FFFu + ((v.i>>16)&1u);
  return (u16)(r>>16);
}

union BfPack { u16 h[8]; bf16x8 v; uint4 u; };

__device__ __forceinline__ uint4 pack8u(const float* __restrict__ p){
  float4 a = *(const float4*)p;
  float4 b = *(const float4*)(p + 4);
  BfPack r;
  r.h[0]=f2b(a.x); r.h[1]=f2b(a.y); r.h[2]=f2b(a.z); r.h[3]=f2b(a.w);
  r.h[4]=f2b(b.x); r.h[5]=f2b(b.y); r.h[6]=f2b(b.z); r.h[7]=f2b(b.w);
  return r.u;
}

// async 16B global -> LDS; LDS dest is wave-uniform base + lane*16
__device__ __forceinline__ void gld_lds16(const u16* g, u16* l){
  __builtin_amdgcn_global_load_lds(
      (const __attribute__((address_space(1))) unsigned int*)g,
      (__attribute__((address_space(3))) unsigned int*)l, 16, 0, 0);
}

// ---------------- kernel 1: f32 -> bf16 for x, w_qkv, w_out ------------------
// 8 floats per thread; exact: x 2,408,448 | wqkv 55,296 | wout 18,432 groups
__global__ __launch_bounds__(256) void k_convert(
    const float* __restrict__ x, const float* __restrict__ wqkv,
    const float* __restrict__ wout,
    u16* __restrict__ xb, u16* __restrict__ wqkvb, u16* __restrict__ woutb)
{
  int idx = (int)blockIdx.x * 256 + threadIdx.x;      // 8-float groups
  const float* src; u16* dst; int off;
  if (idx < 2408448)      { src = x;    dst = xb;    off = idx; }
  else if (idx < 2463744) { src = wqkv; dst = wqkvb; off = idx - 2408448; }
  else                    { src = wout; dst = woutb; off = idx - 2463744; }
  *(uint4*)(dst + (size_t)off*8) = pack8u(src + (size_t)off*8);
}

// ---------------- kernel 2: QKV GEMM ------------------------------------------
// 2-phase K-split pipeline (T3/T4): A-tile stored as two [64][192] half-K
// buffers. All 8 global_load_lds issue up front; s_waitcnt vmcnt(4) + raw
// s_barrier gates phase 0 (buf1 loads stay in flight across the barrier and
// land under phase-0 MFMAs). Chunk-XOR swizzle on source + LDS reads keeps
// ds_read_b128 conflict-free. XCD-bijective block swizzle (2352 = 8*294).
__global__ __launch_bounds__(384, 4) void k_qkv(
    const u16* __restrict__ xb, const u16* __restrict__ wqkvb,
    u16* __restrict__ qkvs)
{
  __shared__ u16 At[2][64][192];   // 49152 B; reused as [64][384] epilogue
  u16* Al = &At[0][0][0];
  const int tid = threadIdx.x;
  const int wv = tid >> 6, lane = tid & 63, quad = lane >> 4, l16 = lane & 15;

  const int bid = (int)blockIdx.x;                    // 2352 blocks
  const int logical = (bid & 7) * 294 + (bid >> 3);   // bijective XCD swizzle
  const int m0 = (logical / 3) * 64;
  const int ng = logical % 3;
  const int n0 = (ng * 6 + wv) * 64;

  // issue both half-tiles: wave wv covers byte range [wv*4096, wv*4096+4096)
  // of each 24576B half; dest linear, source chunk XOR-swizzled with row&7
  {
    const int lane16 = lane << 4;
    #pragma unroll
    for (int h = 0; h < 2; ++h)
      #pragma unroll
      for (int i = 0; i < 4; ++i) {
        const int idx = wv*4096 + i*1024 + lane16;    // byte idx within half
        const int r   = idx / 384;                    // logical row 0..63
        const int c   = (idx % 384) >> 4;             // 16B chunk 0..23
        const int cl  = c ^ (r & 7);                  // swizzled source chunk
        const int m   = m0 + r;
        const int b   = m / 3136, rm = m - b*3136;
        const int hs  = rm / 56, ws_ = rm - hs*56;
        int hh = hs + 3; if (hh >= 56) hh -= 56;      // shifted source coord
        int ww = ws_ + 3; if (ww >= 56) ww -= 56;
        gld_lds16(xb + (size_t)((b*56 + hh)*56 + ww)*384 + h*192 + cl*8,
                  Al + (h*24576 + wv*4096 + i*1024)/2);
      }
  }
  // counted wait: drain the 4 buf0 issues only; buf1 stays in flight
  asm volatile("s_waitcnt vmcnt(4)" ::: "memory");
  __builtin_amdgcn_s_barrier();
  __builtin_amdgcn_sched_barrier(0);

  f32x4 acc[4][4];
  #pragma unroll
  for (int mi = 0; mi < 4; ++mi)
    #pragma unroll
    for (int j = 0; j < 4; ++j) acc[mi][j] = f32x4{0.f,0.f,0.f,0.f};

  const int swz = l16 & 7;     // (row&7) for row = mi*16+l16
  #pragma unroll
  for (int h = 0; h < 2; ++h) {
    const u16* Ab = Al + h*12288;
    #pragma unroll
    for (int k2 = 0; k2 < 6; ++k2) {
      bf16x8 a[4], bb[4];
      const int ck = ((k2*4 + quad) ^ swz) << 3;      // swizzled col (u16)
      #pragma unroll
      for (int mi = 0; mi < 4; ++mi)
        a[mi] = *(const bf16x8*)(Ab + (mi*16 + l16)*192 + ck);
      const int kk = h*6 + k2;
      #pragma unroll
      for (int j = 0; j < 4; ++j)
        bb[j] = *(const bf16x8*)(&wqkvb[(size_t)(n0 + j*16 + l16)*384 + kk*32 + quad*8]);
      #pragma unroll
      for (int mi = 0; mi < 4; ++mi)
        #pragma unroll
        for (int j = 0; j < 4; ++j)
          acc[mi][j] = MFMA16(a[mi], bb[j], acc[mi][j]);
    }
    if (h == 0) __syncthreads();   // drains vmcnt(0): buf1 complete
  }
  __syncthreads();   // A-tile reads done; reuse At as output staging

  #pragma unroll
  for (int mi = 0; mi < 4; ++mi)
    #pragma unroll
    for (int j = 0; j < 4; ++j)
      #pragma unroll
      for (int r = 0; r < 4; ++r) {
        const int row = mi*16 + quad*4 + r;
        const int c = wv*8 + j*2 + (l16 >> 3);        // logical 16B chunk
        Al[row*384 + (((c ^ (row & 7)) << 3) | (l16 & 7))] = f2b(acc[mi][j][r]);
      }
  __syncthreads();

  // cooperative coalesced store: 64 rows x 768 B contiguous spans
  for (int i = tid; i < 64*48; i += 384) {
    int row = i / 48, g = i % 48;
    *(uint4*)(qkvs + (size_t)(m0 + row)*1152 + ng*384 + g*8) =
        *(const uint4*)(Al + row*384 + ((g ^ (row & 7)) << 3));
  }
}

// ---------------- kernel 3: windowed attention, 1 wave per (window, head) -----
// Output written at ORIGINAL (rolled +3) coordinates so k_proj is fully linear.
// P/Vt use stride-64 + chunk-XOR swizzle (not +8 pad): 51856B LDS -> 3 blk/CU.
struct __align__(16) SmemT {
  u16 Vt[4][32][64];    // per-wave V^T [d][pos-swz]; pos 49..63 zeroed
  u16 P[4][64][64];     // per-wave softmax probs, chunk-XOR swizzled
  float relb[4][169];   // per-wave rel-pos table column
};

__global__ __launch_bounds__(256, 3) void k_attn(
    const u16* __restrict__ qkvs, const float* __restrict__ relt,
    u16* __restrict__ attnb)
{
  __shared__ SmemT S;
  const int tid = threadIdx.x;
  const int wv = tid >> 6, lane = tid & 63, quad = lane >> 4, l16 = lane & 15;
  const int blk = (int)blockIdx.x;                 // 3072 blocks
  const int b = blk / 192, r0 = blk % 192, win = r0 / 3, hg = r0 % 3;
  const int hb = win >> 3, wb = win & 7, head = hg*4 + wv;

  for (int i = lane; i < 169; i += 64) S.relb[wv][i] = relt[i*12 + head];

  // stage V^T: lane = pos; col swizzled by (d&7) within 8-u16 chunks
  {
    const int pos = lane;
    u16 vh[32];
    if (pos < 49) {
      int py = pos / 7, px = pos - py*7;
      const uint4* src = (const uint4*)(qkvs +
          (size_t)((b*56 + hb*7+py)*56 + wb*7+px)*1152 + 768 + head*32);
      #pragma unroll
      for (int t = 0; t < 4; ++t) *(uint4*)(&vh[t*8]) = src[t];
    } else {
      #pragma unroll
      for (int t = 0; t < 4; ++t) *(uint4*)(&vh[t*8]) = uint4{0,0,0,0};
    }
    #pragma unroll
    for (int d = 0; d < 32; ++d)
      S.Vt[wv][d][(((pos>>3) ^ (d&7)) << 3) | (pos&7)] = vh[d];
  }

  // Q / K fragments straight from global (A: m=pos, B: n=pos; k = quad*8..)
  bf16x8 aq[4], bk[4];
  #pragma unroll
  for (int mt = 0; mt < 4; ++mt) {
    int pos = mt*16 + l16; if (pos > 48) pos = 48;   // clamp; masked later
    int py = pos / 7, px = pos - py*7;
    const u16* src = qkvs + (size_t)((b*56 + hb*7+py)*56 + wb*7+px)*1152
                   + head*32 + quad*8;
    aq[mt] = *(const bf16x8*)src;          // Q part
    bk[mt] = *(const bf16x8*)(src + 384);  // K part
  }
  __syncthreads();

  // QK^T
  f32x4 sc[4][4];
  #pragma unroll
  for (int mt = 0; mt < 4; ++mt)
    #pragma unroll
    for (int n = 0; n < 4; ++n) {
      f32x4 z = {0.f,0.f,0.f,0.f};
      sc[mt][n] = MFMA16(aq[mt], bk[n], z);
    }

  // bias + mask + softmax
  #pragma unroll
  for (int mt = 0; mt < 4; ++mt)
    #pragma unroll
    for (int r = 0; r < 4; ++r) {
      const int q = mt*16 + quad*4 + r;
      const int qy = q / 7, qx = q - qy*7;
      #pragma unroll
      for (int n = 0; n < 4; ++n) {
        const int key = n*16 + l16;
        float s = sc[mt][n][r] * 0.17677669529663687f;   // 1/sqrt(32)
        if (key < 49 && q < 49) {
          const int ky = key / 7, kx = key - ky*7;
          s += S.relb[wv][(ky - qy + 6)*13 + (kx - qx + 6)];
          if (hb == 7 && ((qy >= 4) != (ky >= 4))) s = NEGHUGE;  // UL mask
        } else {
          s = NEGHUGE;
        }
        sc[mt][n][r] = s;
      }
      float mx = fmaxf(fmaxf(sc[mt][0][r], sc[mt][1][r]),
                       fmaxf(sc[mt][2][r], sc[mt][3][r]));
      mx = fmaxf(mx, __shfl_xor(mx, 1));
      mx = fmaxf(mx, __shfl_xor(mx, 2));
      mx = fmaxf(mx, __shfl_xor(mx, 4));
      mx = fmaxf(mx, __shfl_xor(mx, 8));
      float sum = 0.f;
      #pragma unroll
      for (int n = 0; n < 4; ++n) {
        float p = exp2f((sc[mt][n][r] - mx) * 1.4426950408889634f);
        sc[mt][n][r] = p; sum += p;
      }
      sum += __shfl_xor(sum, 1);
      sum += __shfl_xor(sum, 2);
      sum += __shfl_xor(sum, 4);
      sum += __shfl_xor(sum, 8);
      const float rinv = 1.0f / sum;
      #pragma unroll
      for (int n = 0; n < 4; ++n)
        S.P[wv][q][(((n*2 + (l16>>3)) ^ (q&7)) << 3) | (l16&7)] =
            f2b(sc[mt][n][r] * rinv);
    }
  __syncthreads();

  // PV; store at rolled (+3) coordinates
  const int sw = l16 & 7;
  #pragma unroll
  for (int mt = 0; mt < 4; ++mt) {
    bf16x8 ap0 = *(const bf16x8*)(&S.P[wv][mt*16 + l16][(quad ^ sw) << 3]);
    bf16x8 ap1 = *(const bf16x8*)(&S.P[wv][mt*16 + l16][((quad+4) ^ sw) << 3]);
    #pragma unroll
    for (int n2 = 0; n2 < 2; ++n2) {
      bf16x8 bv0 = *(const bf16x8*)(&S.Vt[wv][n2*16 + l16][(quad ^ sw) << 3]);
      bf16x8 bv1 = *(const bf16x8*)(&S.Vt[wv][n2*16 + l16][((quad+4) ^ sw) << 3]);
      f32x4 o = {0.f,0.f,0.f,0.f};
      o = MFMA16(ap0, bv0, o);
      o = MFMA16(ap1, bv1, o);
      #pragma unroll
      for (int r = 0; r < 4; ++r) {
        int q = mt*16 + quad*4 + r;
        if (q < 49) {
          int py = q / 7, px = q - py*7;
          int hh = hb*7 + py + 3; if (hh >= 56) hh -= 56;  // inverse roll here
          int ww = wb*7 + px + 3; if (ww >= 56) ww -= 56;
          attnb[(size_t)((b*56 + hh)*56 + ww)*384
                + head*32 + n2*16 + l16] = f2b(o[r]);
        }
      }
    }
  }
}

// ---------------- kernel 4: out = attn @ w_out^T + b_out, fully linear -------
// Same 2-phase K-split pipeline as k_qkv (vmcnt(2) counted wait).
__global__ __launch_bounds__(384, 4) void k_proj(
    const u16* __restrict__ attnb, const u16* __restrict__ woutb,
    const float* __restrict__ bout, float* __restrict__ out)
{
  __shared__ u16 At[2][32][192];   // 24576 B
  u16* Al = &At[0][0][0];
  const int tid = threadIdx.x;
  const int wv = tid >> 6, lane = tid & 63, quad = lane >> 4, l16 = lane & 15;
  const int m0 = (int)blockIdx.x * 32;               // 1568 blocks
  const int n0 = wv * 64;                            // 6 waves cover N=384

  {
    const int lane16 = lane << 4;
    #pragma unroll
    for (int h = 0; h < 2; ++h)
      #pragma unroll
      for (int i = 0; i < 2; ++i) {
        const int idx = wv*2048 + i*1024 + lane16;   // byte idx within half
        const int r   = idx / 384;                   // 0..31
        const int c   = (idx % 384) >> 4;            // 0..23
        const int cl  = c ^ (r & 7);
        gld_lds16(attnb + (size_t)(m0 + r)*384 + h*192 + cl*8,
                  Al + (h*12288 + wv*2048 + i*1024)/2);
      }
  }
  asm volatile("s_waitcnt vmcnt(2)" ::: "memory");
  __builtin_amdgcn_s_barrier();
  __builtin_amdgcn_sched_barrier(0);

  f32x4 acc[2][4];
  #pragma unroll
  for (int mi = 0; mi < 2; ++mi)
    #pragma unroll
    for (int j = 0; j < 4; ++j) acc[mi][j] = f32x4{0.f,0.f,0.f,0.f};

  const int swz = l16 & 7;
  #pragma unroll
  for (int h = 0; h < 2; ++h) {
    const u16* Ab = Al + h*6144;
    #pragma unroll
    for (int k2 = 0; k2 < 6; ++k2) {
      bf16x8 a[2], bb[4];
      const int ck = ((k2*4 + quad) ^ swz) << 3;
      #pragma unroll
      for (int mi = 0; mi < 2; ++mi)
        a[mi] = *(const bf16x8*)(Ab + (mi*16 + l16)*192 + ck);
      const int kk = h*6 + k2;
      #pragma unroll
      for (int j = 0; j < 4; ++j)
        bb[j] = *(const bf16x8*)(&woutb[(size_t)(n0 + j*16 + l16)*384 + kk*32 + quad*8]);
      #pragma unroll
      for (int mi = 0; mi < 2; ++mi)
        #pragma unroll
        for (int j = 0; j < 4; ++j)
          acc[mi][j] = MFMA16(a[mi], bb[j], acc[mi][j]);
    }
    if (h == 0) __syncthreads();   // buf1 complete
  }

  float bias[4];
  #pragma unroll
  for (int j = 0; j < 4; ++j) bias[j] = bout[n0 + j*16 + l16];

  // linear stores; j-inner so the 4x64B segments of each 256B span merge
  #pragma unroll
  for (int mi = 0; mi < 2; ++mi)
    #pragma unroll
    for (int r = 0; r < 4; ++r) {
      const int m = m0 + mi*16 + quad*4 + r;
      float* dst = out + (size_t)m*384 + n0;
      #pragma unroll
      for (int j = 0; j < 4; ++j)
        dst[j*16 + l16] = acc[mi][j][r] + bias[j];
    }
}

extern "C" void kernel_launch(void* const* d_in, const int* in_sizes, int n_in,
                              void* d_out, int out_size, void* d_ws, size_t ws_size,
                              hipStream_t stream) {
  const float* x    = (const float*)d_in[0];
  const float* wqkv = (const float*)d_in[1];
  const float* wout = (const float*)d_in[2];
  const float* bout = (const float*)d_in[3];
  const float* relt = (const float*)d_in[4];

  char* ws = (char*)d_ws;
  u16* qkvs  = (u16*)(ws);                        // 115,605,504 B
  u16* wqkvb = (u16*)(ws + 115605504);            //     884,736 B
  u16* woutb = (u16*)(ws + 116490240);            //     294,912 B
  // xb (bf16 x) and attnb alias the same slot: xb is dead before k_attn runs
  u16* xb    = (u16*)(ws + 116785152);            //  38,535,168 B
  u16* attnb = (u16*)(ws + 116785152);            //  38,535,168 B
  float* outp = (float*)d_out;

  k_convert<<<9696, 256, 0, stream>>>(x, wqkv, wout, xb, wqkvb, woutb);
  k_qkv<<<2352, 384, 0, stream>>>(xb, wqkvb, qkvs);
  k_attn<<<3072, 256, 0, stream>>>(qkvs, relt, attnb);
  k_proj<<<1568, 384, 0, stream>>>(attnb, woutb, bout, outp);
}